// Round 11
// baseline (536.241 us; speedup 1.0000x reference)
//
#include <hip/hip_runtime.h>
#include <hip/hip_bf16.h>

#define NN 10000
#define EE 60000
#define HIDD 128
#define NH 8
#define INNERD 1024
#define FFD 512
#define KVQ 3072
#define KVQS 3200

using u16 = unsigned short;
using u32 = unsigned int;

typedef __bf16 bf16x8 __attribute__((ext_vector_type(8)));
typedef float f32x4 __attribute__((ext_vector_type(4)));

__device__ __forceinline__ float u2f(u32 u) { return __uint_as_float(u << 16); }
__device__ __forceinline__ u16 f2b(float f) {  // RNE
  u32 x = __float_as_uint(f);
  return (u16)((x + 0x7fffu + ((x >> 16) & 1u)) >> 16);
}
__device__ __forceinline__ float gelu_f(float x) {
  return 0.5f * x * (1.0f + erff(x * 0.70710678118654752f));
}

// ---------------- dtype detect (runtime hedge, flag=1 means f32 inputs)
__global__ void detect_k(const u32* __restrict__ xw, int* __restrict__ flag) {
  if (threadIdx.x == 0 && blockIdx.x == 0) {
    int wild = 0;
    for (int i = 0; i < 256; ++i) {
      float v = u2f(xw[i] & 0xffffu);
      if (!(fabsf(v) < 1e4f)) ++wild;
    }
    *flag = (wild > 16) ? 1 : 0;
  }
}

#define NCVT 30
struct CvtArgs { const void* src[NCVT]; int cnt[NCVT]; int ntot; };

__global__ __launch_bounds__(256) void convert_k(CvtArgs a, const int* __restrict__ flag,
                                                 float* __restrict__ dst) {
  const int i = blockIdx.x * 256 + threadIdx.x;
  if (i >= a.ntot) return;
  int t = 0, off = i;
  while (off >= a.cnt[t]) { off -= a.cnt[t]; ++t; }
  const float v = (*flag) ? ((const float*)a.src[t])[off]
                          : u2f(((const u16*)a.src[t])[off]);
  dst[i] = v;
}

// ---------------- batched weight transpose: W[K][N] -> WT bf16 [N][K]
struct TT { const void* s; long off; u16* d; int K; int N; };
struct TTab { TT m[28]; };

__global__ __launch_bounds__(256) void transT_k(TTab tt, const int* __restrict__ flag) {
  const TT m = tt.m[blockIdx.z];
  const int n0 = blockIdx.x * 32, k0 = blockIdx.y * 32;
  if (n0 >= m.N || k0 >= m.K) return;
  __shared__ float tile[32][33];
  const int c = threadIdx.x;
  const int f32in = *flag;
  for (int i = threadIdx.y; i < 32; i += 8) {
    const long gi = m.off + (long)(k0 + i) * m.N + n0 + c;
    tile[i][c] = f32in ? ((const float*)m.s)[gi] : u2f(((const u16*)m.s)[gi]);
  }
  __syncthreads();
  for (int i = threadIdx.y; i < 32; i += 8)
    m.d[(size_t)(n0 + i) * m.K + k0 + c] = f2b(tile[c][i]);
}

// ---------------- CSR build
__global__ __launch_bounds__(256) void hist_k(const int* __restrict__ ei0,
                                              const int* __restrict__ ei1,
                                              int* __restrict__ hist) {
  const int e = blockIdx.x * 256 + threadIdx.x;
  if (e >= EE) return;
  const int et = blockIdx.y;
  const int* ei = et ? ei1 : ei0;
  atomicAdd(&hist[et * NN + ei[EE + e]], 1);
}

__global__ __launch_bounds__(1024) void scan2_k(const int* __restrict__ hist,
                                                int* __restrict__ rowptr,
                                                int* __restrict__ cursor) {
  const int et = blockIdx.x;
  const int* h = hist + et * NN;
  int* rp = rowptr + et * (NN + 1);
  int* cu = cursor + et * NN;
  __shared__ int wsum[16];
  __shared__ int carrySm;
  const int t = threadIdx.x, lane = t & 63, wid = t >> 6;
  if (t == 0) carrySm = 0;
  __syncthreads();
  for (int base = 0; base < NN; base += 1024) {
    const int idx = base + t;
    const int v = (idx < NN) ? h[idx] : 0;
    int x = v;
#pragma unroll
    for (int off = 1; off < 64; off <<= 1) {
      int y = __shfl_up(x, off);
      if (lane >= off) x += y;
    }
    if (lane == 63) wsum[wid] = x;
    __syncthreads();
    if (wid == 0) {
      int s = (lane < 16) ? wsum[lane] : 0;
#pragma unroll
      for (int off = 1; off < 16; off <<= 1) {
        int y = __shfl_up(s, off);
        if (lane >= off) s += y;
      }
      if (lane < 16) wsum[lane] = s;
    }
    __syncthreads();
    const int waveoff = (wid > 0) ? wsum[wid - 1] : 0;
    const int incl = x + waveoff + carrySm;
    if (idx < NN) { rp[idx] = incl - v; cu[idx] = incl - v; }
    __syncthreads();
    if (t == 1023) carrySm = incl;
    __syncthreads();
  }
  if (t == 0) rp[NN] = carrySm;
}

__global__ __launch_bounds__(256) void scat_k(const int* __restrict__ ei0,
                                              const int* __restrict__ ei1,
                                              int* __restrict__ cursor,
                                              int* __restrict__ srcs) {
  const int e = blockIdx.x * 256 + threadIdx.x;
  if (e >= EE) return;
  const int et = blockIdx.y;
  const int* ei = et ? ei1 : ei0;
  const int s = ei[e], d = ei[EE + e];
  const int pos = atomicAdd(&cursor[et * NN + d], 1);
  srcs[et * EE + pos] = s;
}

// ---------------- embed both types: h = x @ Win + bin + te + pos; writes f32 + bf16 mirror
__global__ __launch_bounds__(128) void embed2_k(
    const void* __restrict__ x0, const float* __restrict__ Win0,
    const float* __restrict__ bin0, const float* __restrict__ te0,
    const void* __restrict__ pos0, float* __restrict__ h0, u16* __restrict__ h80,
    const void* __restrict__ x1, const float* __restrict__ Win1,
    const float* __restrict__ bin1, const float* __restrict__ te1,
    const void* __restrict__ pos1, float* __restrict__ h1, u16* __restrict__ h81,
    const int* __restrict__ flag) {
  const int ty = blockIdx.y;
  const void* x = ty ? x1 : x0;
  const float* Win = ty ? Win1 : Win0;
  const float* bin = ty ? bin1 : bin0;
  const float* te = ty ? te1 : te0;
  const void* pos = ty ? pos1 : pos0;
  float* h = ty ? h1 : h0;
  u16* h8 = ty ? h81 : h80;
  __shared__ float Ws[64][128];
  __shared__ float xs[16][64];
  const int f32in = *flag;
  const int j = threadIdx.x;
  const int base = blockIdx.x * 16;
  for (int i = 0; i < 64; ++i) Ws[i][j] = Win[i * 128 + j];
  for (int r = 0; r < 8; ++r) {
    int idx = r * 128 + j;
    int row = idx >> 6, k = idx & 63;
    size_t gi = (size_t)(base + row) * 64 + k;
    xs[row][k] = f32in ? ((const float*)x)[gi] : u2f(((const u16*)x)[gi]);
  }
  __syncthreads();
  float bj = bin[j] + te[j];
  for (int row = 0; row < 16; ++row) {
    size_t gi = (size_t)(base + row) * 128 + j;
    float pv = f32in ? ((const float*)pos)[gi] : u2f(((const u16*)pos)[gi]);
    float acc = bj + pv;
#pragma unroll
    for (int k = 0; k < 64; ++k) acc += xs[row][k] * Ws[k][j];
    h[(size_t)(base + row) * 128 + j] = acc;
    h8[(size_t)(base + row) * 128 + j] = f2b(acc);
  }
}

// ---------------- MFMA GEMM (A bf16), dual-task via blockIdx.z
// MODE 2: kvqs (N=3200, K=128): cols<3072 -> Cb bf16 stride 3072; cols>=3072 -> Cf f32 stride 128
// MODE 3: gelu -> Cb bf16 (stride N), K=128
// MODE 4: + add(f32) -> Cf f32 AND Cb bf16 (stride N), K=512 (BK=32 loop)
// MODE 5: Wout (K=128): runtime oflag -> Cf f32 else Cb bf16
struct MG {
  const u16* A; const u16* WT;
  const float* b0; const float* b1; const float* b2; const float* b3;
  const float* add; float* Cf; u16* Cb; const int* oflag;
};

template <int MODE>
__global__ __launch_bounds__(256) void mgemm2_k(MG g0, MG g1, int M, int N, int K) {
  const MG g = blockIdx.z ? g1 : g0;
  const int t = threadIdx.x;
  const int lane = t & 63, wid = t >> 6;
  const int bm = blockIdx.y * 128, bn = blockIdx.x * 64;
  const int rg = lane >> 4, rr = lane & 15;
  f32x4 acc[2][4];
#pragma unroll
  for (int i = 0; i < 2; ++i)
#pragma unroll
    for (int j = 0; j < 4; ++j) acc[i][j] = (f32x4){0.f, 0.f, 0.f, 0.f};

  if constexpr (MODE != 4) {
    // ---- K=128 full-stage: one sync, no k-loop ----
    __shared__ __align__(16) u16 Asl[128][136];
    __shared__ __align__(16) u16 Bsl[64][136];
    const int ar = t >> 1, ah = (t & 1) << 6;   // 0/64
    const int garow = bm + ar;
#pragma unroll
    for (int j = 0; j < 8; ++j) {
      uint4 av = {0, 0, 0, 0};
      if (garow < M) av = *reinterpret_cast<const uint4*>(g.A + (size_t)garow * 128 + ah + j * 8);
      *reinterpret_cast<uint4*>(&Asl[ar][ah + j * 8]) = av;
    }
    const int wr = t >> 2, wk = (t & 3) << 5;   // 0,32,64,96
#pragma unroll
    for (int j = 0; j < 4; ++j) {
      const uint4 bv = *reinterpret_cast<const uint4*>(g.WT + (size_t)(bn + wr) * 128 + wk + j * 8);
      *reinterpret_cast<uint4*>(&Bsl[wr][wk + j * 8]) = bv;
    }
    __syncthreads();
#pragma unroll
    for (int kk = 0; kk < 4; ++kk) {
      bf16x8 af[2], bfr[4];
#pragma unroll
      for (int mi = 0; mi < 2; ++mi)
        af[mi] = *reinterpret_cast<const bf16x8*>(&Asl[wid * 32 + mi * 16 + rr][rg * 8 + kk * 32]);
#pragma unroll
      for (int ni = 0; ni < 4; ++ni)
        bfr[ni] = *reinterpret_cast<const bf16x8*>(&Bsl[ni * 16 + rr][rg * 8 + kk * 32]);
#pragma unroll
      for (int mi = 0; mi < 2; ++mi)
#pragma unroll
        for (int ni = 0; ni < 4; ++ni)
          acc[mi][ni] = __builtin_amdgcn_mfma_f32_16x16x32_bf16(af[mi], bfr[ni], acc[mi][ni], 0, 0, 0);
    }
  } else {
    // ---- K=512: BK=32 loop ----
    __shared__ __align__(16) u16 Asl[128][40];
    __shared__ __align__(16) u16 Bsl[64][40];
    const int ar = t >> 1;
    const int ah = (t & 1) << 4;
    const int wr = t >> 2;
    const int wk = (t & 3) << 3;
    for (int k0 = 0; k0 < K; k0 += 32) {
      const int garow = bm + ar;
      uint4 a0 = {0, 0, 0, 0}, a1 = {0, 0, 0, 0};
      if (garow < M) {
        const u16* ap = g.A + (size_t)garow * K + k0 + ah;
        a0 = *reinterpret_cast<const uint4*>(ap);
        a1 = *reinterpret_cast<const uint4*>(ap + 8);
      }
      *reinterpret_cast<uint4*>(&Asl[ar][ah]) = a0;
      *reinterpret_cast<uint4*>(&Asl[ar][ah + 8]) = a1;
      const uint4 bv = *reinterpret_cast<const uint4*>(g.WT + (size_t)(bn + wr) * K + k0 + wk);
      *reinterpret_cast<uint4*>(&Bsl[wr][wk]) = bv;
      __syncthreads();
      bf16x8 af[2], bfr[4];
#pragma unroll
      for (int mi = 0; mi < 2; ++mi)
        af[mi] = *reinterpret_cast<const bf16x8*>(&Asl[wid * 32 + mi * 16 + rr][rg * 8]);
#pragma unroll
      for (int ni = 0; ni < 4; ++ni)
        bfr[ni] = *reinterpret_cast<const bf16x8*>(&Bsl[ni * 16 + rr][rg * 8]);
#pragma unroll
      for (int mi = 0; mi < 2; ++mi)
#pragma unroll
        for (int ni = 0; ni < 4; ++ni)
          acc[mi][ni] = __builtin_amdgcn_mfma_f32_16x16x32_bf16(af[mi], bfr[ni], acc[mi][ni], 0, 0, 0);
      __syncthreads();
    }
  }

  const int f32o = (MODE == 5) ? *g.oflag : 0;
#pragma unroll
  for (int mi = 0; mi < 2; ++mi) {
#pragma unroll
    for (int ni = 0; ni < 4; ++ni) {
      const int col = bn + ni * 16 + rr;
      float bcol;
      if (MODE == 2) {
        const int seg = col >> 10;
        const float* bp = (seg == 0) ? g.b0 : ((seg == 1) ? g.b1 : ((seg == 2) ? g.b2 : g.b3));
        bcol = bp[col & 1023];
      } else {
        bcol = g.b0[col];
      }
#pragma unroll
      for (int r = 0; r < 4; ++r) {
        const int row = bm + wid * 32 + mi * 16 + rg * 4 + r;
        if (row >= M) continue;
        float v = acc[mi][ni][r] + bcol;
        if (MODE == 2) {
          if (col < KVQ) g.Cb[(size_t)row * KVQ + col] = f2b(v);
          else           g.Cf[(size_t)row * HIDD + (col - KVQ)] = v;
        } else if (MODE == 3) {
          v = gelu_f(v);
          g.Cb[(size_t)row * N + col] = f2b(v);
        } else if (MODE == 4) {
          v += g.add[(size_t)row * N + col];
          g.Cf[(size_t)row * N + col] = v;
          g.Cb[(size_t)row * N + col] = f2b(v);
        } else {  // MODE 5
          if (f32o) g.Cf[(size_t)row * N + col] = v;
          else      g.Cb[(size_t)row * N + col] = f2b(v);
        }
      }
    }
  }
}

// ---------------- fused flash attention + beta gate + LayerNorm, both edge types (y = et)
struct ABL {
  const float* Wb; const float* hrow; const float* lgam; const float* lbet;
  const float* xr; float* r; u16* r8;
};

__global__ __launch_bounds__(256) void attnbl2_k(
    const u16* __restrict__ kvqJ, const u16* __restrict__ kvqM,
    const int* __restrict__ rowptr, const int* __restrict__ srcs,
    ABL bl0, ABL bl1) {
  const int et = blockIdx.y;
  const u16* kvqS = et ? kvqM : kvqJ;
  const u16* kvqD = et ? kvqJ : kvqM;
  const int* rp = rowptr + et * (NN + 1);
  const int* sr = srcs + et * EE;
  const ABL pb = et ? bl1 : bl0;
  const int d = (blockIdx.x * 256 + threadIdx.x) >> 6;
  const int lane = threadIdx.x & 63;
  const u16* qp = kvqD + (size_t)d * KVQ + 2048 + lane * 16;
  uint4 q0 = *reinterpret_cast<const uint4*>(qp);
  uint4 q1 = *reinterpret_cast<const uint4*>(qp + 8);
  float qf[16];
  {
    u32 w[8] = {q0.x, q0.y, q0.z, q0.w, q1.x, q1.y, q1.z, q1.w};
#pragma unroll
    for (int i = 0; i < 8; ++i) { qf[2*i] = u2f(w[i] & 0xffffu); qf[2*i+1] = u2f(w[i] >> 16); }
  }
  float m = -INFINITY, den = 0.f;
  float acc[16];
#pragma unroll
  for (int i = 0; i < 16; ++i) acc[i] = 0.f;
  const int beg = rp[d], end = rp[d + 1];

  auto dot8 = [&](const uint4& a, const uint4& b) -> float {
    float p = 0.f;
    const u32 w[8] = {a.x, a.y, a.z, a.w, b.x, b.y, b.z, b.w};
#pragma unroll
    for (int i = 0; i < 8; ++i) {
      p += qf[2*i] * u2f(w[i] & 0xffffu);
      p += qf[2*i+1] * u2f(w[i] >> 16);
    }
    return p;
  };
  auto wred = [&](float p) -> float {
    p += __shfl_xor(p, 1);
    p += __shfl_xor(p, 2);
    p += __shfl_xor(p, 4);
    return p * 0.088388347648318447f;  // 1/sqrt(128)
  };

  int idx = beg;
  for (; idx + 2 <= end; idx += 2) {
    const int s0 = sr[idx], s1 = sr[idx + 1];
    const u16* kp0 = kvqS + (size_t)s0 * KVQ + lane * 16;
    const u16* kp1 = kvqS + (size_t)s1 * KVQ + lane * 16;
    const uint4 a0 = *reinterpret_cast<const uint4*>(kp0);
    const uint4 a1 = *reinterpret_cast<const uint4*>(kp0 + 8);
    const uint4 av0 = *reinterpret_cast<const uint4*>(kp0 + 1024);
    const uint4 av1 = *reinterpret_cast<const uint4*>(kp0 + 1024 + 8);
    const uint4 b0 = *reinterpret_cast<const uint4*>(kp1);
    const uint4 b1 = *reinterpret_cast<const uint4*>(kp1 + 8);
    const uint4 bv0 = *reinterpret_cast<const uint4*>(kp1 + 1024);
    const uint4 bv1 = *reinterpret_cast<const uint4*>(kp1 + 1024 + 8);
    const float lg0 = wred(dot8(a0, a1));
    const float lg1 = wred(dot8(b0, b1));
    const float nm = fmaxf(m, fmaxf(lg0, lg1));
    const float cor = __expf(m - nm);
    const float p0 = __expf(lg0 - nm);
    const float p1 = __expf(lg1 - nm);
    den = den * cor + p0 + p1;
    const u32 wa[8] = {av0.x, av0.y, av0.z, av0.w, av1.x, av1.y, av1.z, av1.w};
    const u32 wb[8] = {bv0.x, bv0.y, bv0.z, bv0.w, bv1.x, bv1.y, bv1.z, bv1.w};
#pragma unroll
    for (int i = 0; i < 8; ++i) {
      acc[2*i]   = (acc[2*i]   * cor + p0 * u2f(wa[i] & 0xffffu)) + p1 * u2f(wb[i] & 0xffffu);
      acc[2*i+1] = (acc[2*i+1] * cor + p0 * u2f(wa[i] >> 16))     + p1 * u2f(wb[i] >> 16);
    }
    m = nm;
  }
  if (idx < end) {
    const int s0 = sr[idx];
    const u16* kp0 = kvqS + (size_t)s0 * KVQ + lane * 16;
    const uint4 a0 = *reinterpret_cast<const uint4*>(kp0);
    const uint4 a1 = *reinterpret_cast<const uint4*>(kp0 + 8);
    const uint4 av0 = *reinterpret_cast<const uint4*>(kp0 + 1024);
    const uint4 av1 = *reinterpret_cast<const uint4*>(kp0 + 1024 + 8);
    const float lg = wred(dot8(a0, a1));
    const float nm = fmaxf(m, lg);
    const float cor = __expf(m - nm);
    const float p = __expf(lg - nm);
    den = den * cor + p;
    const u32 w[8] = {av0.x, av0.y, av0.z, av0.w, av1.x, av1.y, av1.z, av1.w};
#pragma unroll
    for (int i = 0; i < 8; ++i) {
      acc[2*i]   = acc[2*i]   * cor + p * u2f(w[i] & 0xffffu);
      acc[2*i+1] = acc[2*i+1] * cor + p * u2f(w[i] >> 16);
    }
    m = nm;
  }

  const float inv = 0.125f / (den + 1e-16f);
  float o[16];
#pragma unroll
  for (int i = 0; i < 16; ++i) {
    float tv = acc[i] * inv;
    tv += __shfl_xor(tv, 8);
    tv += __shfl_xor(tv, 16);
    tv += __shfl_xor(tv, 32);
    o[i] = tv;
  }

  const int g8 = (lane & 7) * 16;
  float x[16], hd[16];
  {
    const float* xrp = pb.xr + (size_t)d * HIDD + g8;
    const float* hp  = pb.hrow + (size_t)d * HIDD + g8;
#pragma unroll
    for (int i = 0; i < 16; i += 4) {
      const float4 xv = *reinterpret_cast<const float4*>(xrp + i);
      const float4 hv = *reinterpret_cast<const float4*>(hp + i);
      x[i] = xv.x; x[i+1] = xv.y; x[i+2] = xv.z; x[i+3] = xv.w;
      hd[i] = hv.x; hd[i+1] = hv.y; hd[i+2] = hv.z; hd[i+3] = hv.w;
    }
  }
  float s = 0.f;
#pragma unroll
  for (int i = 0; i < 16; ++i) {
    s += o[i] * pb.Wb[g8 + i] + x[i] * pb.Wb[128 + g8 + i]
       + (o[i] - x[i]) * pb.Wb[256 + g8 + i];
  }
  s += __shfl_xor(s, 1);
  s += __shfl_xor(s, 2);
  s += __shfl_xor(s, 4);
  const float beta = 1.f / (1.f + expf(-s));
  float v[16];
  float psum = 0.f;
#pragma unroll
  for (int i = 0; i < 16; ++i) {
    v[i] = hd[i] + beta * x[i] + (1.f - beta) * o[i];
    psum += v[i];
  }
  psum += __shfl_xor(psum, 1);
  psum += __shfl_xor(psum, 2);
  psum += __shfl_xor(psum, 4);
  const float mu = psum * (1.f / 128.f);
  float pvar = 0.f;
#pragma unroll
  for (int i = 0; i < 16; ++i) {
    const float dv = v[i] - mu;
    pvar += dv * dv;
  }
  pvar += __shfl_xor(pvar, 1);
  pvar += __shfl_xor(pvar, 2);
  pvar += __shfl_xor(pvar, 4);
  const float rstd = rsqrtf(pvar * (1.f / 128.f) + 1e-5f);
  float r[16];
#pragma unroll
  for (int i = 0; i < 16; ++i)
    r[i] = (v[i] - mu) * rstd * pb.lgam[g8 + i] + pb.lbet[g8 + i];
  if (lane < 8) {
    float* rp_ = pb.r + (size_t)d * HIDD + g8;
#pragma unroll
    for (int i = 0; i < 16; i += 4)
      *reinterpret_cast<float4*>(rp_ + i) = make_float4(r[i], r[i+1], r[i+2], r[i+3]);
    u32 pk[8];
#pragma unroll
    for (int i = 0; i < 8; ++i)
      pk[i] = (u32)f2b(r[2*i]) | ((u32)f2b(r[2*i+1]) << 16);
    uint4* r8p = reinterpret_cast<uint4*>(pb.r8 + (size_t)d * HIDD + g8);
    r8p[0] = (uint4){pk[0], pk[1], pk[2], pk[3]};
    r8p[1] = (uint4){pk[4], pk[5], pk[6], pk[7]};
  }
}

extern "C" void kernel_launch(void* const* d_in, const int* in_sizes, int n_in,
                              void* d_out, int out_size, void* d_ws, size_t ws_size,
                              hipStream_t stream) {
  char* w = (char*)d_ws;
  auto carve = [&](size_t bytes) { void* p = (void*)w; w += (bytes + 255) & ~(size_t)255; return p; };
  float* h_b[2];  h_b[0] = (float*)carve((size_t)NN * HIDD * 4); h_b[1] = (float*)carve((size_t)NN * HIDD * 4);
  u16* h8_b[2];   h8_b[0] = (u16*)carve((size_t)NN * HIDD * 2);  h8_b[1] = (u16*)carve((size_t)NN * HIDD * 2);
  float* rb_b[2]; rb_b[0] = (float*)carve((size_t)NN * HIDD * 4); rb_b[1] = (float*)carve((size_t)NN * HIDD * 4);
  u16* rb8_b[2];  rb8_b[0] = (u16*)carve((size_t)NN * HIDD * 2);  rb8_b[1] = (u16*)carve((size_t)NN * HIDD * 2);
  float* xr_b[2]; xr_b[0] = (float*)carve((size_t)NN * HIDD * 4); xr_b[1] = (float*)carve((size_t)NN * HIDD * 4);
  u16* kvqJ = (u16*)carve((size_t)NN * KVQ * 2);
  u16* kvqM = (u16*)carve((size_t)NN * KVQ * 2);
  u16* mid8_b[2] = {kvqJ, kvqM};  // alias: FFN mid (bf16) after attn done
  int* histb  = (int*)carve(2 * NN * 4);
  int* rowptr = (int*)carve(2 * (NN + 1) * 4);
  int* cursor = (int*)carve(2 * NN * 4);
  int* srcsb  = (int*)carve(2 * EE * 4);
  int* flagp  = (int*)carve(256);
  const int totCvt = 2 * 26752 + 2 * 7168;  // 67840 floats (validated round 9)
  float* wf = (float*)carve((size_t)totCvt * 4);
  u16* wtp = (u16*)carve((size_t)(4 * KVQS * HIDD + 8 * HIDD * FFD + 2 * HIDD * HIDD) * 2);

  // ---- f32 conversion table (small tensors) ----
  CvtArgs ca; int nc = 0; int cum = 0;
  auto addc = [&](int inIdx, int n) -> float* {
    ca.src[nc] = d_in[inIdx]; ca.cnt[nc] = n; float* p = wf + cum; cum += n; ++nc; return p;
  };
  const float *WinF[2], *binF[2], *teF[2], *lngF[2], *lnbF[2], *b1F[2], *b2F[2], *WoutF[2], *boutF[2];
  const void* x_p[2]; const void* pos_p[2];
  for (int t = 0; t < 2; ++t) {
    const int o = t * 13;
    x_p[t] = d_in[o + 0];
    WinF[t] = addc(o + 1, 64 * HIDD);
    binF[t] = addc(o + 2, HIDD);
    pos_p[t] = d_in[o + 3];
    teF[t]  = addc(o + 4, HIDD);
    lngF[t] = addc(o + 5, 2 * HIDD);
    lnbF[t] = addc(o + 6, 2 * HIDD);
    b1F[t]  = addc(o + 8, 2 * FFD);
    b2F[t]  = addc(o + 10, 2 * HIDD);
    WoutF[t] = addc(o + 11, HIDD * HIDD);  // kept in table (unused) to preserve layout
    boutF[t] = addc(o + 12, HIDD);
  }
  const float *WbF[2], *bqF[2], *bkF[2], *bvF[2], *bsF[2];
  const int* ei_e[2];
  for (int et = 0; et < 2; ++et) {
    const int o = 26 + et * 10;
    WbF[et] = addc(o + 4, 2 * 384);
    bqF[et] = addc(o + 5, 2 * INNERD);
    bkF[et] = addc(o + 6, 2 * INNERD);
    bvF[et] = addc(o + 7, 2 * INNERD);
    bsF[et] = addc(o + 8, 2 * HIDD);
    ei_e[et] = (const int*)d_in[o + 9];
  }
  ca.ntot = cum;  // == 67840 == totCvt

  // ---- transpose table: per (et,l) [Wk_et|Wv_et|Wq_OTHER|Ws_OTHER] -> [3200][128]; W1,W2; Wout
  TTab tt; int ntt = 0; u16* tcur = wtp;
  auto addT = [&](const void* s, long off, int K, int N, u16* dst) {
    tt.m[ntt] = {s, off, dst, K, N}; ++ntt;
  };
  u16* kvqWT[2][2];
  for (int et = 0; et < 2; ++et) {
    const int o  = 26 + et * 10;
    const int oq = 26 + (1 - et) * 10;  // OTHER edge type (Q, Ws weights)
    for (int l = 0; l < 2; ++l) {
      u16* base = tcur; tcur += (size_t)KVQS * HIDD;
      kvqWT[et][l] = base;
      addT(d_in[o + 1],  (long)l * HIDD * INNERD, HIDD, INNERD, base);
      addT(d_in[o + 2],  (long)l * HIDD * INNERD, HIDD, INNERD, base + 1024 * HIDD);
      addT(d_in[oq + 0], (long)l * HIDD * INNERD, HIDD, INNERD, base + 2048 * HIDD);
      addT(d_in[oq + 3], (long)l * HIDD * HIDD,   HIDD, HIDD,   base + 3072 * HIDD);
    }
  }
  u16 *W1T[2][2], *W2T[2][2], *WoutT[2];
  for (int t = 0; t < 2; ++t) {
    const int o = t * 13;
    for (int l = 0; l < 2; ++l) {
      W1T[t][l] = tcur; addT(d_in[o + 7], (long)l * HIDD * FFD, HIDD, FFD, tcur); tcur += (size_t)HIDD * FFD;
      W2T[t][l] = tcur; addT(d_in[o + 9], (long)l * FFD * HIDD, FFD, HIDD, tcur); tcur += (size_t)FFD * HIDD;
    }
  }
  for (int t = 0; t < 2; ++t) {
    const int o = t * 13;
    WoutT[t] = tcur; addT(d_in[o + 11], 0, HIDD, HIDD, tcur); tcur += (size_t)HIDD * HIDD;
  }
  // ntt == 26

  const dim3 blk(256);
  const int MB128 = (NN + 127) / 128; // 79

  // ---- prep ----
  detect_k<<<1, 64, 0, stream>>>((const u32*)d_in[0], flagp);
  convert_k<<<(cum + 255) / 256, blk, 0, stream>>>(ca, flagp, wf);
  transT_k<<<dim3(32, 16, 26), dim3(32, 8), 0, stream>>>(tt, flagp);
  hipMemsetAsync(histb, 0, 2 * NN * 4, stream);
  hist_k<<<dim3((EE + 255) / 256, 2), blk, 0, stream>>>(ei_e[0], ei_e[1], histb);
  scan2_k<<<2, 1024, 0, stream>>>(histb, rowptr, cursor);
  scat_k<<<dim3((EE + 255) / 256, 2), blk, 0, stream>>>(ei_e[0], ei_e[1], cursor, srcsb);

  // ---- embed (both types, f32 + bf16) ----
  embed2_k<<<dim3(NN / 16, 2), 128, 0, stream>>>(
      x_p[0], WinF[0], binF[0], teF[0], pos_p[0], h_b[0], h8_b[0],
      x_p[1], WinF[1], binF[1], teF[1], pos_p[1], h_b[1], h8_b[1], flagp);

  for (int l = 0; l < 2; ++l) {
    // kvq+S projections: A=h8_j -> [K_jm|V_jm|Q_mj|S_mj] (xr_j); A=h8_m -> ... (xr_m)
    MG gj = {h8_b[0], kvqWT[0][l], bkF[0] + l * INNERD, bvF[0] + l * INNERD,
             bqF[1] + l * INNERD, bsF[1] + l * HIDD, nullptr, xr_b[0], kvqJ, nullptr};
    MG gm = {h8_b[1], kvqWT[1][l], bkF[1] + l * INNERD, bvF[1] + l * INNERD,
             bqF[0] + l * INNERD, bsF[0] + l * HIDD, nullptr, xr_b[1], kvqM, nullptr};
    mgemm2_k<2><<<dim3(KVQS / 64, MB128, 2), blk, 0, stream>>>(gj, gm, NN, KVQS, HIDD);
    // attention + beta + LN (fused): y=0 jm->dst mach(type1); y=1 mj->dst job(type0)
    ABL bl0 = {WbF[0] + l * 384, h_b[1], lngF[1] + l * HIDD, lnbF[1] + l * HIDD,
               xr_b[1], rb_b[1], rb8_b[1]};
    ABL bl1 = {WbF[1] + l * 384, h_b[0], lngF[0] + l * HIDD, lnbF[0] + l * HIDD,
               xr_b[0], rb_b[0], rb8_b[0]};
    attnbl2_k<<<dim3(NN / 4, 2), blk, 0, stream>>>(kvqJ, kvqM, rowptr, srcsb, bl0, bl1);
    // FFN W1 (gelu -> bf16 mid), both types
    MG w1j = {rb8_b[0], W1T[0][l], b1F[0] + l * FFD, nullptr, nullptr, nullptr,
              nullptr, nullptr, mid8_b[0], nullptr};
    MG w1m = {rb8_b[1], W1T[1][l], b1F[1] + l * FFD, nullptr, nullptr, nullptr,
              nullptr, nullptr, mid8_b[1], nullptr};
    mgemm2_k<3><<<dim3(FFD / 64, MB128, 2), blk, 0, stream>>>(w1j, w1m, NN, FFD, HIDD);
    // FFN W2 (+residual rb) -> h f32 + h8 bf16, both types
    MG w2j = {mid8_b[0], W2T[0][l], b2F[0] + l * HIDD, nullptr, nullptr, nullptr,
              rb_b[0], h_b[0], h8_b[0], nullptr};
    MG w2m = {mid8_b[1], W2T[1][l], b2F[1] + l * HIDD, nullptr, nullptr, nullptr,
              rb_b[1], h_b[1], h8_b[1], nullptr};
    mgemm2_k<4><<<dim3(HIDD / 64, MB128, 2), blk, 0, stream>>>(w2j, w2m, NN, HIDD, FFD);
  }
  // output projections (bf16 MFMA, runtime-flag output dtype), both types
  MG o0 = {h8_b[0], WoutT[0], boutF[0], nullptr, nullptr, nullptr,
           nullptr, (float*)d_out, (u16*)d_out, flagp};
  MG o1 = {h8_b[1], WoutT[1], boutF[1], nullptr, nullptr, nullptr,
           nullptr, (float*)d_out + (size_t)NN * HIDD, (u16*)d_out + (size_t)NN * HIDD, flagp};
  mgemm2_k<5><<<dim3(HIDD / 64, MB128, 2), blk, 0, stream>>>(o0, o1, NN, HIDD, HIDD);
}

// Round 12
// 454.981 us; speedup vs baseline: 1.1786x; 1.1786x over previous
//
#include <hip/hip_runtime.h>
#include <hip/hip_bf16.h>

#define NN 10000
#define EE 60000
#define HIDD 128
#define NH 8
#define INNERD 1024
#define FFD 512
#define KVQ 3072
#define KVQS 3200

using u16 = unsigned short;
using u32 = unsigned int;

typedef __bf16 bf16x8 __attribute__((ext_vector_type(8)));
typedef float f32x4 __attribute__((ext_vector_type(4)));

__device__ __forceinline__ float u2f(u32 u) { return __uint_as_float(u << 16); }
__device__ __forceinline__ u16 f2b(float f) {  // RNE
  u32 x = __float_as_uint(f);
  return (u16)((x + 0x7fffu + ((x >> 16) & 1u)) >> 16);
}
__device__ __forceinline__ float gelu_f(float x) {
  return 0.5f * x * (1.0f + erff(x * 0.70710678118654752f));
}

// ---------------- dtype detect (runtime hedge, flag=1 means f32 inputs)
__global__ void detect_k(const u32* __restrict__ xw, int* __restrict__ flag) {
  if (threadIdx.x == 0 && blockIdx.x == 0) {
    int wild = 0;
    for (int i = 0; i < 256; ++i) {
      float v = u2f(xw[i] & 0xffffu);
      if (!(fabsf(v) < 1e4f)) ++wild;
    }
    *flag = (wild > 16) ? 1 : 0;
  }
}

#define NCVT 30
struct CvtArgs { const void* src[NCVT]; int cnt[NCVT]; int ntot; };

__global__ __launch_bounds__(256) void convert_k(CvtArgs a, const int* __restrict__ flag,
                                                 float* __restrict__ dst) {
  const int i = blockIdx.x * 256 + threadIdx.x;
  if (i >= a.ntot) return;
  int t = 0, off = i;
  while (off >= a.cnt[t]) { off -= a.cnt[t]; ++t; }
  const float v = (*flag) ? ((const float*)a.src[t])[off]
                          : u2f(((const u16*)a.src[t])[off]);
  dst[i] = v;
}

// ---------------- batched weight transpose: W[K][N] -> WT bf16 [N][K]
struct TT { const void* s; long off; u16* d; int K; int N; };
struct TTab { TT m[28]; };

__global__ __launch_bounds__(256) void transT_k(TTab tt, const int* __restrict__ flag) {
  const TT m = tt.m[blockIdx.z];
  const int n0 = blockIdx.x * 32, k0 = blockIdx.y * 32;
  if (n0 >= m.N || k0 >= m.K) return;
  __shared__ float tile[32][33];
  const int c = threadIdx.x;
  const int f32in = *flag;
  for (int i = threadIdx.y; i < 32; i += 8) {
    const long gi = m.off + (long)(k0 + i) * m.N + n0 + c;
    tile[i][c] = f32in ? ((const float*)m.s)[gi] : u2f(((const u16*)m.s)[gi]);
  }
  __syncthreads();
  for (int i = threadIdx.y; i < 32; i += 8)
    m.d[(size_t)(n0 + i) * m.K + k0 + c] = f2b(tile[c][i]);
}

// ---------------- CSR build
__global__ __launch_bounds__(256) void hist_k(const int* __restrict__ ei0,
                                              const int* __restrict__ ei1,
                                              int* __restrict__ hist) {
  const int e = blockIdx.x * 256 + threadIdx.x;
  if (e >= EE) return;
  const int et = blockIdx.y;
  const int* ei = et ? ei1 : ei0;
  atomicAdd(&hist[et * NN + ei[EE + e]], 1);
}

__global__ __launch_bounds__(1024) void scan2_k(const int* __restrict__ hist,
                                                int* __restrict__ rowptr,
                                                int* __restrict__ cursor) {
  const int et = blockIdx.x;
  const int* h = hist + et * NN;
  int* rp = rowptr + et * (NN + 1);
  int* cu = cursor + et * NN;
  __shared__ int wsum[16];
  __shared__ int carrySm;
  const int t = threadIdx.x, lane = t & 63, wid = t >> 6;
  if (t == 0) carrySm = 0;
  __syncthreads();
  for (int base = 0; base < NN; base += 1024) {
    const int idx = base + t;
    const int v = (idx < NN) ? h[idx] : 0;
    int x = v;
#pragma unroll
    for (int off = 1; off < 64; off <<= 1) {
      int y = __shfl_up(x, off);
      if (lane >= off) x += y;
    }
    if (lane == 63) wsum[wid] = x;
    __syncthreads();
    if (wid == 0) {
      int s = (lane < 16) ? wsum[lane] : 0;
#pragma unroll
      for (int off = 1; off < 16; off <<= 1) {
        int y = __shfl_up(s, off);
        if (lane >= off) s += y;
      }
      if (lane < 16) wsum[lane] = s;
    }
    __syncthreads();
    const int waveoff = (wid > 0) ? wsum[wid - 1] : 0;
    const int incl = x + waveoff + carrySm;
    if (idx < NN) { rp[idx] = incl - v; cu[idx] = incl - v; }
    __syncthreads();
    if (t == 1023) carrySm = incl;
    __syncthreads();
  }
  if (t == 0) rp[NN] = carrySm;
}

__global__ __launch_bounds__(256) void scat_k(const int* __restrict__ ei0,
                                              const int* __restrict__ ei1,
                                              int* __restrict__ cursor,
                                              int* __restrict__ srcs) {
  const int e = blockIdx.x * 256 + threadIdx.x;
  if (e >= EE) return;
  const int et = blockIdx.y;
  const int* ei = et ? ei1 : ei0;
  const int s = ei[e], d = ei[EE + e];
  const int pos = atomicAdd(&cursor[et * NN + d], 1);
  srcs[et * EE + pos] = s;
}

// ---------------- embed both types: h = x @ Win + bin + te + pos; writes f32 + bf16 mirror
__global__ __launch_bounds__(128) void embed2_k(
    const void* __restrict__ x0, const float* __restrict__ Win0,
    const float* __restrict__ bin0, const float* __restrict__ te0,
    const void* __restrict__ pos0, float* __restrict__ h0, u16* __restrict__ h80,
    const void* __restrict__ x1, const float* __restrict__ Win1,
    const float* __restrict__ bin1, const float* __restrict__ te1,
    const void* __restrict__ pos1, float* __restrict__ h1, u16* __restrict__ h81,
    const int* __restrict__ flag) {
  const int ty = blockIdx.y;
  const void* x = ty ? x1 : x0;
  const float* Win = ty ? Win1 : Win0;
  const float* bin = ty ? bin1 : bin0;
  const float* te = ty ? te1 : te0;
  const void* pos = ty ? pos1 : pos0;
  float* h = ty ? h1 : h0;
  u16* h8 = ty ? h81 : h80;
  __shared__ float Ws[64][128];
  __shared__ float xs[16][64];
  const int f32in = *flag;
  const int j = threadIdx.x;
  const int base = blockIdx.x * 16;
  for (int i = 0; i < 64; ++i) Ws[i][j] = Win[i * 128 + j];
  for (int r = 0; r < 8; ++r) {
    int idx = r * 128 + j;
    int row = idx >> 6, k = idx & 63;
    size_t gi = (size_t)(base + row) * 64 + k;
    xs[row][k] = f32in ? ((const float*)x)[gi] : u2f(((const u16*)x)[gi]);
  }
  __syncthreads();
  float bj = bin[j] + te[j];
  for (int row = 0; row < 16; ++row) {
    size_t gi = (size_t)(base + row) * 128 + j;
    float pv = f32in ? ((const float*)pos)[gi] : u2f(((const u16*)pos)[gi]);
    float acc = bj + pv;
#pragma unroll
    for (int k = 0; k < 64; ++k) acc += xs[row][k] * Ws[k][j];
    h[(size_t)(base + row) * 128 + j] = acc;
    h8[(size_t)(base + row) * 128 + j] = f2b(acc);
  }
}

// ---------------- MFMA GEMM (A bf16), BK=32 loop (proven round-10 config), dual via blockIdx.z
// MODE 2: kvqs (N=3200): cols<3072 -> Cb bf16 stride 3072; cols>=3072 -> Cf f32 stride 128
// MODE 3: gelu -> Cb bf16 (stride N)
// MODE 4: + add(f32) -> Cf f32 AND Cb bf16 (stride N)
// MODE 5: Wout: runtime oflag -> Cf f32 else Cb bf16
struct MG {
  const u16* A; const u16* WT;
  const float* b0; const float* b1; const float* b2; const float* b3;
  const float* add; float* Cf; u16* Cb; const int* oflag;
};

template <int MODE>
__global__ __launch_bounds__(256) void mgemm2_k(MG g0, MG g1, int M, int N, int K) {
  const MG g = blockIdx.z ? g1 : g0;
  __shared__ __align__(16) u16 Asl[128][40];   // 80B rows: 2-way bank aliasing (free)
  __shared__ __align__(16) u16 Bsl[64][40];
  const int t = threadIdx.x;
  const int lane = t & 63, wid = t >> 6;
  const int bm = blockIdx.y * 128, bn = blockIdx.x * 64;
  const int rg = lane >> 4, rr = lane & 15;
  f32x4 acc[2][4];
#pragma unroll
  for (int i = 0; i < 2; ++i)
#pragma unroll
    for (int j = 0; j < 4; ++j) acc[i][j] = (f32x4){0.f, 0.f, 0.f, 0.f};
  const int ar = t >> 1;            // 0..127 A row
  const int ah = (t & 1) << 4;      // 0/16 k-offset
  const int wr = t >> 2;            // 0..63 WT row
  const int wk = (t & 3) << 3;      // 0,8,16,24

  for (int k0 = 0; k0 < K; k0 += 32) {
    const int garow = bm + ar;
    uint4 a0 = {0, 0, 0, 0}, a1 = {0, 0, 0, 0};
    if (garow < M) {
      const u16* ap = g.A + (size_t)garow * K + k0 + ah;
      a0 = *reinterpret_cast<const uint4*>(ap);
      a1 = *reinterpret_cast<const uint4*>(ap + 8);
    }
    *reinterpret_cast<uint4*>(&Asl[ar][ah]) = a0;
    *reinterpret_cast<uint4*>(&Asl[ar][ah + 8]) = a1;
    const uint4 bv = *reinterpret_cast<const uint4*>(g.WT + (size_t)(bn + wr) * K + k0 + wk);
    *reinterpret_cast<uint4*>(&Bsl[wr][wk]) = bv;
    __syncthreads();
    bf16x8 af[2], bfr[4];
#pragma unroll
    for (int mi = 0; mi < 2; ++mi)
      af[mi] = *reinterpret_cast<const bf16x8*>(&Asl[wid * 32 + mi * 16 + rr][rg * 8]);
#pragma unroll
    for (int ni = 0; ni < 4; ++ni)
      bfr[ni] = *reinterpret_cast<const bf16x8*>(&Bsl[ni * 16 + rr][rg * 8]);
#pragma unroll
    for (int mi = 0; mi < 2; ++mi)
#pragma unroll
      for (int ni = 0; ni < 4; ++ni)
        acc[mi][ni] = __builtin_amdgcn_mfma_f32_16x16x32_bf16(af[mi], bfr[ni], acc[mi][ni], 0, 0, 0);
    __syncthreads();
  }

  const int f32o = (MODE == 5) ? *g.oflag : 0;
#pragma unroll
  for (int mi = 0; mi < 2; ++mi) {
#pragma unroll
    for (int ni = 0; ni < 4; ++ni) {
      const int col = bn + ni * 16 + rr;
      float bcol;
      if (MODE == 2) {
        const int seg = col >> 10;
        const float* bp = (seg == 0) ? g.b0 : ((seg == 1) ? g.b1 : ((seg == 2) ? g.b2 : g.b3));
        bcol = bp[col & 1023];
      } else {
        bcol = g.b0[col];
      }
#pragma unroll
      for (int r = 0; r < 4; ++r) {
        const int row = bm + wid * 32 + mi * 16 + rg * 4 + r;
        if (row >= M) continue;
        float v = acc[mi][ni][r] + bcol;
        if (MODE == 2) {
          if (col < KVQ) g.Cb[(size_t)row * KVQ + col] = f2b(v);
          else           g.Cf[(size_t)row * HIDD + (col - KVQ)] = v;
        } else if (MODE == 3) {
          v = gelu_f(v);
          g.Cb[(size_t)row * N + col] = f2b(v);
        } else if (MODE == 4) {
          v += g.add[(size_t)row * N + col];
          g.Cf[(size_t)row * N + col] = v;
          g.Cb[(size_t)row * N + col] = f2b(v);
        } else {  // MODE 5
          if (f32o) g.Cf[(size_t)row * N + col] = v;
          else      g.Cb[(size_t)row * N + col] = f2b(v);
        }
      }
    }
  }
}

// ---------------- fused flash attention + beta gate + LayerNorm, both edge types (y = et)
struct ABL {
  const float* Wb; const float* hrow; const float* lgam; const float* lbet;
  const float* xr; float* r; u16* r8;
};

__global__ __launch_bounds__(256) void attnbl2_k(
    const u16* __restrict__ kvqJ, const u16* __restrict__ kvqM,
    const int* __restrict__ rowptr, const int* __restrict__ srcs,
    ABL bl0, ABL bl1) {
  const int et = blockIdx.y;
  const u16* kvqS = et ? kvqM : kvqJ;
  const u16* kvqD = et ? kvqJ : kvqM;
  const int* rp = rowptr + et * (NN + 1);
  const int* sr = srcs + et * EE;
  const ABL pb = et ? bl1 : bl0;
  const int d = (blockIdx.x * 256 + threadIdx.x) >> 6;
  const int lane = threadIdx.x & 63;
  const u16* qp = kvqD + (size_t)d * KVQ + 2048 + lane * 16;
  uint4 q0 = *reinterpret_cast<const uint4*>(qp);
  uint4 q1 = *reinterpret_cast<const uint4*>(qp + 8);
  float qf[16];
  {
    u32 w[8] = {q0.x, q0.y, q0.z, q0.w, q1.x, q1.y, q1.z, q1.w};
#pragma unroll
    for (int i = 0; i < 8; ++i) { qf[2*i] = u2f(w[i] & 0xffffu); qf[2*i+1] = u2f(w[i] >> 16); }
  }
  float m = -INFINITY, den = 0.f;
  float acc[16];
#pragma unroll
  for (int i = 0; i < 16; ++i) acc[i] = 0.f;
  const int beg = rp[d], end = rp[d + 1];

  auto dot8 = [&](const uint4& a, const uint4& b) -> float {
    float p = 0.f;
    const u32 w[8] = {a.x, a.y, a.z, a.w, b.x, b.y, b.z, b.w};
#pragma unroll
    for (int i = 0; i < 8; ++i) {
      p += qf[2*i] * u2f(w[i] & 0xffffu);
      p += qf[2*i+1] * u2f(w[i] >> 16);
    }
    return p;
  };
  auto wred = [&](float p) -> float {
    p += __shfl_xor(p, 1);
    p += __shfl_xor(p, 2);
    p += __shfl_xor(p, 4);
    return p * 0.088388347648318447f;  // 1/sqrt(128)
  };

  int idx = beg;
  for (; idx + 2 <= end; idx += 2) {
    const int s0 = sr[idx], s1 = sr[idx + 1];
    const u16* kp0 = kvqS + (size_t)s0 * KVQ + lane * 16;
    const u16* kp1 = kvqS + (size_t)s1 * KVQ + lane * 16;
    const uint4 a0 = *reinterpret_cast<const uint4*>(kp0);
    const uint4 a1 = *reinterpret_cast<const uint4*>(kp0 + 8);
    const uint4 av0 = *reinterpret_cast<const uint4*>(kp0 + 1024);
    const uint4 av1 = *reinterpret_cast<const uint4*>(kp0 + 1024 + 8);
    const uint4 b0 = *reinterpret_cast<const uint4*>(kp1);
    const uint4 b1 = *reinterpret_cast<const uint4*>(kp1 + 8);
    const uint4 bv0 = *reinterpret_cast<const uint4*>(kp1 + 1024);
    const uint4 bv1 = *reinterpret_cast<const uint4*>(kp1 + 1024 + 8);
    const float lg0 = wred(dot8(a0, a1));
    const float lg1 = wred(dot8(b0, b1));
    const float nm = fmaxf(m, fmaxf(lg0, lg1));
    const float cor = __expf(m - nm);
    const float p0 = __expf(lg0 - nm);
    const float p1 = __expf(lg1 - nm);
    den = den * cor + p0 + p1;
    const u32 wa[8] = {av0.x, av0.y, av0.z, av0.w, av1.x, av1.y, av1.z, av1.w};
    const u32 wb[8] = {bv0.x, bv0.y, bv0.z, bv0.w, bv1.x, bv1.y, bv1.z, bv1.w};
#pragma unroll
    for (int i = 0; i < 8; ++i) {
      acc[2*i]   = (acc[2*i]   * cor + p0 * u2f(wa[i] & 0xffffu)) + p1 * u2f(wb[i] & 0xffffu);
      acc[2*i+1] = (acc[2*i+1] * cor + p0 * u2f(wa[i] >> 16))     + p1 * u2f(wb[i] >> 16);
    }
    m = nm;
  }
  if (idx < end) {
    const int s0 = sr[idx];
    const u16* kp0 = kvqS + (size_t)s0 * KVQ + lane * 16;
    const uint4 a0 = *reinterpret_cast<const uint4*>(kp0);
    const uint4 a1 = *reinterpret_cast<const uint4*>(kp0 + 8);
    const uint4 av0 = *reinterpret_cast<const uint4*>(kp0 + 1024);
    const uint4 av1 = *reinterpret_cast<const uint4*>(kp0 + 1024 + 8);
    const float lg = wred(dot8(a0, a1));
    const float nm = fmaxf(m, lg);
    const float cor = __expf(m - nm);
    const float p = __expf(lg - nm);
    den = den * cor + p;
    const u32 w[8] = {av0.x, av0.y, av0.z, av0.w, av1.x, av1.y, av1.z, av1.w};
#pragma unroll
    for (int i = 0; i < 8; ++i) {
      acc[2*i]   = acc[2*i]   * cor + p * u2f(w[i] & 0xffffu);
      acc[2*i+1] = acc[2*i+1] * cor + p * u2f(w[i] >> 16);
    }
    m = nm;
  }

  const float inv = 0.125f / (den + 1e-16f);
  float o[16];
#pragma unroll
  for (int i = 0; i < 16; ++i) {
    float tv = acc[i] * inv;
    tv += __shfl_xor(tv, 8);
    tv += __shfl_xor(tv, 16);
    tv += __shfl_xor(tv, 32);
    o[i] = tv;
  }

  const int g8 = (lane & 7) * 16;
  float x[16], hd[16];
  {
    const float* xrp = pb.xr + (size_t)d * HIDD + g8;
    const float* hp  = pb.hrow + (size_t)d * HIDD + g8;
#pragma unroll
    for (int i = 0; i < 16; i += 4) {
      const float4 xv = *reinterpret_cast<const float4*>(xrp + i);
      const float4 hv = *reinterpret_cast<const float4*>(hp + i);
      x[i] = xv.x; x[i+1] = xv.y; x[i+2] = xv.z; x[i+3] = xv.w;
      hd[i] = hv.x; hd[i+1] = hv.y; hd[i+2] = hv.z; hd[i+3] = hv.w;
    }
  }
  float s = 0.f;
#pragma unroll
  for (int i = 0; i < 16; ++i) {
    s += o[i] * pb.Wb[g8 + i] + x[i] * pb.Wb[128 + g8 + i]
       + (o[i] - x[i]) * pb.Wb[256 + g8 + i];
  }
  s += __shfl_xor(s, 1);
  s += __shfl_xor(s, 2);
  s += __shfl_xor(s, 4);
  const float beta = 1.f / (1.f + expf(-s));
  float v[16];
  float psum = 0.f;
#pragma unroll
  for (int i = 0; i < 16; ++i) {
    v[i] = hd[i] + beta * x[i] + (1.f - beta) * o[i];
    psum += v[i];
  }
  psum += __shfl_xor(psum, 1);
  psum += __shfl_xor(psum, 2);
  psum += __shfl_xor(psum, 4);
  const float mu = psum * (1.f / 128.f);
  float pvar = 0.f;
#pragma unroll
  for (int i = 0; i < 16; ++i) {
    const float dv = v[i] - mu;
    pvar += dv * dv;
  }
  pvar += __shfl_xor(pvar, 1);
  pvar += __shfl_xor(pvar, 2);
  pvar += __shfl_xor(pvar, 4);
  const float rstd = rsqrtf(pvar * (1.f / 128.f) + 1e-5f);
  float r[16];
#pragma unroll
  for (int i = 0; i < 16; ++i)
    r[i] = (v[i] - mu) * rstd * pb.lgam[g8 + i] + pb.lbet[g8 + i];
  if (lane < 8) {
    float* rp_ = pb.r + (size_t)d * HIDD + g8;
#pragma unroll
    for (int i = 0; i < 16; i += 4)
      *reinterpret_cast<float4*>(rp_ + i) = make_float4(r[i], r[i+1], r[i+2], r[i+3]);
    u32 pk[8];
#pragma unroll
    for (int i = 0; i < 8; ++i)
      pk[i] = (u32)f2b(r[2*i]) | ((u32)f2b(r[2*i+1]) << 16);
    uint4* r8p = reinterpret_cast<uint4*>(pb.r8 + (size_t)d * HIDD + g8);
    r8p[0] = (uint4){pk[0], pk[1], pk[2], pk[3]};
    r8p[1] = (uint4){pk[4], pk[5], pk[6], pk[7]};
  }
}

extern "C" void kernel_launch(void* const* d_in, const int* in_sizes, int n_in,
                              void* d_out, int out_size, void* d_ws, size_t ws_size,
                              hipStream_t stream) {
  char* w = (char*)d_ws;
  auto carve = [&](size_t bytes) { void* p = (void*)w; w += (bytes + 255) & ~(size_t)255; return p; };
  float* h_b[2];  h_b[0] = (float*)carve((size_t)NN * HIDD * 4); h_b[1] = (float*)carve((size_t)NN * HIDD * 4);
  u16* h8_b[2];   h8_b[0] = (u16*)carve((size_t)NN * HIDD * 2);  h8_b[1] = (u16*)carve((size_t)NN * HIDD * 2);
  float* rb_b[2]; rb_b[0] = (float*)carve((size_t)NN * HIDD * 4); rb_b[1] = (float*)carve((size_t)NN * HIDD * 4);
  u16* rb8_b[2];  rb8_b[0] = (u16*)carve((size_t)NN * HIDD * 2);  rb8_b[1] = (u16*)carve((size_t)NN * HIDD * 2);
  float* xr_b[2]; xr_b[0] = (float*)carve((size_t)NN * HIDD * 4); xr_b[1] = (float*)carve((size_t)NN * HIDD * 4);
  u16* kvqJ = (u16*)carve((size_t)NN * KVQ * 2);
  u16* kvqM = (u16*)carve((size_t)NN * KVQ * 2);
  u16* mid8_b[2] = {kvqJ, kvqM};  // alias: FFN mid (bf16) after attn done
  int* histb  = (int*)carve(2 * NN * 4);
  int* rowptr = (int*)carve(2 * (NN + 1) * 4);
  int* cursor = (int*)carve(2 * NN * 4);
  int* srcsb  = (int*)carve(2 * EE * 4);
  int* flagp  = (int*)carve(256);
  const int totCvt = 2 * 26752 + 2 * 7168;  // 67840 floats (validated round 9)
  float* wf = (float*)carve((size_t)totCvt * 4);
  u16* wtp = (u16*)carve((size_t)(4 * KVQS * HIDD + 8 * HIDD * FFD + 2 * HIDD * HIDD) * 2);

  // ---- f32 conversion table (small tensors) ----
  CvtArgs ca; int nc = 0; int cum = 0;
  auto addc = [&](int inIdx, int n) -> float* {
    ca.src[nc] = d_in[inIdx]; ca.cnt[nc] = n; float* p = wf + cum; cum += n; ++nc; return p;
  };
  const float *WinF[2], *binF[2], *teF[2], *lngF[2], *lnbF[2], *b1F[2], *b2F[2], *WoutF[2], *boutF[2];
  const void* x_p[2]; const void* pos_p[2];
  for (int t = 0; t < 2; ++t) {
    const int o = t * 13;
    x_p[t] = d_in[o + 0];
    WinF[t] = addc(o + 1, 64 * HIDD);
    binF[t] = addc(o + 2, HIDD);
    pos_p[t] = d_in[o + 3];
    teF[t]  = addc(o + 4, HIDD);
    lngF[t] = addc(o + 5, 2 * HIDD);
    lnbF[t] = addc(o + 6, 2 * HIDD);
    b1F[t]  = addc(o + 8, 2 * FFD);
    b2F[t]  = addc(o + 10, 2 * HIDD);
    WoutF[t] = addc(o + 11, HIDD * HIDD);  // kept in table (unused) to preserve layout
    boutF[t] = addc(o + 12, HIDD);
  }
  const float *WbF[2], *bqF[2], *bkF[2], *bvF[2], *bsF[2];
  const int* ei_e[2];
  for (int et = 0; et < 2; ++et) {
    const int o = 26 + et * 10;
    WbF[et] = addc(o + 4, 2 * 384);
    bqF[et] = addc(o + 5, 2 * INNERD);
    bkF[et] = addc(o + 6, 2 * INNERD);
    bvF[et] = addc(o + 7, 2 * INNERD);
    bsF[et] = addc(o + 8, 2 * HIDD);
    ei_e[et] = (const int*)d_in[o + 9];
  }
  ca.ntot = cum;  // == 67840 == totCvt

  // ---- transpose table: per (et,l) [Wk_et|Wv_et|Wq_OTHER|Ws_OTHER] -> [3200][128]; W1,W2; Wout
  TTab tt; int ntt = 0; u16* tcur = wtp;
  auto addT = [&](const void* s, long off, int K, int N, u16* dst) {
    tt.m[ntt] = {s, off, dst, K, N}; ++ntt;
  };
  u16* kvqWT[2][2];
  for (int et = 0; et < 2; ++et) {
    const int o  = 26 + et * 10;
    const int oq = 26 + (1 - et) * 10;  // OTHER edge type (Q, Ws weights)
    for (int l = 0; l < 2; ++l) {
      u16* base = tcur; tcur += (size_t)KVQS * HIDD;
      kvqWT[et][l] = base;
      addT(d_in[o + 1],  (long)l * HIDD * INNERD, HIDD, INNERD, base);
      addT(d_in[o + 2],  (long)l * HIDD * INNERD, HIDD, INNERD, base + 1024 * HIDD);
      addT(d_in[oq + 0], (long)l * HIDD * INNERD, HIDD, INNERD, base + 2048 * HIDD);
      addT(d_in[oq + 3], (long)l * HIDD * HIDD,   HIDD, HIDD,   base + 3072 * HIDD);
    }
  }
  u16 *W1T[2][2], *W2T[2][2], *WoutT[2];
  for (int t = 0; t < 2; ++t) {
    const int o = t * 13;
    for (int l = 0; l < 2; ++l) {
      W1T[t][l] = tcur; addT(d_in[o + 7], (long)l * HIDD * FFD, HIDD, FFD, tcur); tcur += (size_t)HIDD * FFD;
      W2T[t][l] = tcur; addT(d_in[o + 9], (long)l * FFD * HIDD, FFD, HIDD, tcur); tcur += (size_t)FFD * HIDD;
    }
  }
  for (int t = 0; t < 2; ++t) {
    const int o = t * 13;
    WoutT[t] = tcur; addT(d_in[o + 11], 0, HIDD, HIDD, tcur); tcur += (size_t)HIDD * HIDD;
  }
  // ntt == 26

  const dim3 blk(256);
  const int MB128 = (NN + 127) / 128; // 79

  // ---- prep ----
  detect_k<<<1, 64, 0, stream>>>((const u32*)d_in[0], flagp);
  convert_k<<<(cum + 255) / 256, blk, 0, stream>>>(ca, flagp, wf);
  transT_k<<<dim3(32, 16, 26), dim3(32, 8), 0, stream>>>(tt, flagp);
  hipMemsetAsync(histb, 0, 2 * NN * 4, stream);
  hist_k<<<dim3((EE + 255) / 256, 2), blk, 0, stream>>>(ei_e[0], ei_e[1], histb);
  scan2_k<<<2, 1024, 0, stream>>>(histb, rowptr, cursor);
  scat_k<<<dim3((EE + 255) / 256, 2), blk, 0, stream>>>(ei_e[0], ei_e[1], cursor, srcsb);

  // ---- embed (both types, f32 + bf16) ----
  embed2_k<<<dim3(NN / 16, 2), 128, 0, stream>>>(
      x_p[0], WinF[0], binF[0], teF[0], pos_p[0], h_b[0], h8_b[0],
      x_p[1], WinF[1], binF[1], teF[1], pos_p[1], h_b[1], h8_b[1], flagp);

  for (int l = 0; l < 2; ++l) {
    // kvq+S projections: A=h8_j -> [K_jm|V_jm|Q_mj|S_mj] (xr_j); A=h8_m -> ... (xr_m)
    MG gj = {h8_b[0], kvqWT[0][l], bkF[0] + l * INNERD, bvF[0] + l * INNERD,
             bqF[1] + l * INNERD, bsF[1] + l * HIDD, nullptr, xr_b[0], kvqJ, nullptr};
    MG gm = {h8_b[1], kvqWT[1][l], bkF[1] + l * INNERD, bvF[1] + l * INNERD,
             bqF[0] + l * INNERD, bsF[0] + l * HIDD, nullptr, xr_b[1], kvqM, nullptr};
    mgemm2_k<2><<<dim3(KVQS / 64, MB128, 2), blk, 0, stream>>>(gj, gm, NN, KVQS, HIDD);
    // attention + beta + LN (fused): y=0 jm->dst mach(type1); y=1 mj->dst job(type0)
    ABL bl0 = {WbF[0] + l * 384, h_b[1], lngF[1] + l * HIDD, lnbF[1] + l * HIDD,
               xr_b[1], rb_b[1], rb8_b[1]};
    ABL bl1 = {WbF[1] + l * 384, h_b[0], lngF[0] + l * HIDD, lnbF[0] + l * HIDD,
               xr_b[0], rb_b[0], rb8_b[0]};
    attnbl2_k<<<dim3(NN / 4, 2), blk, 0, stream>>>(kvqJ, kvqM, rowptr, srcsb, bl0, bl1);
    // FFN W1 (gelu -> bf16 mid), both types
    MG w1j = {rb8_b[0], W1T[0][l], b1F[0] + l * FFD, nullptr, nullptr, nullptr,
              nullptr, nullptr, mid8_b[0], nullptr};
    MG w1m = {rb8_b[1], W1T[1][l], b1F[1] + l * FFD, nullptr, nullptr, nullptr,
              nullptr, nullptr, mid8_b[1], nullptr};
    mgemm2_k<3><<<dim3(FFD / 64, MB128, 2), blk, 0, stream>>>(w1j, w1m, NN, FFD, HIDD);
    // FFN W2 (+residual rb) -> h f32 + h8 bf16, both types
    MG w2j = {mid8_b[0], W2T[0][l], b2F[0] + l * HIDD, nullptr, nullptr, nullptr,
              rb_b[0], h_b[0], h8_b[0], nullptr};
    MG w2m = {mid8_b[1], W2T[1][l], b2F[1] + l * HIDD, nullptr, nullptr, nullptr,
              rb_b[1], h_b[1], h8_b[1], nullptr};
    mgemm2_k<4><<<dim3(HIDD / 64, MB128, 2), blk, 0, stream>>>(w2j, w2m, NN, HIDD, FFD);
  }
  // output projections (bf16 MFMA, runtime-flag output dtype), both types
  MG o0 = {h8_b[0], WoutT[0], boutF[0], nullptr, nullptr, nullptr,
           nullptr, (float*)d_out, (u16*)d_out, flagp};
  MG o1 = {h8_b[1], WoutT[1], boutF[1], nullptr, nullptr, nullptr,
           nullptr, (float*)d_out + (size_t)NN * HIDD, (u16*)d_out + (size_t)NN * HIDD, flagp};
  mgemm2_k<5><<<dim3(HIDD / 64, MB128, 2), blk, 0, stream>>>(o0, o1, NN, HIDD, HIDD);
}